// Round 12
// baseline (223.789 us; speedup 1.0000x reference)
//
#include <hip/hip_runtime.h>

// RGCN 2-layer, N=100000, E=3200000, R=8, H=C=16.
// r12: coalesced-scatter partition. Both partition passes counting-sort the
// block's edges in LDS, then write each bucket run LINEARLY (wave-coalesced
// stores, ~20x fewer L2 write transactions than per-lane scatter).
// init(cursors) -> part1 (coarse 49-way) -> part2 (fine 32-way per coarse
// slice) -> conv(embed->bf16) -> 2x layer (unchanged from r11):
// Phase A (node,rel) counting sort in LDS; Phase B segmented sums via
// indicator-MFMA over 32-edge batches; Phase C 4 rel-block MFMAs + root MFMA
// + fused relu / log_softmax. All X gathers bf16 (L2-resident table).

constexpr int NN = 100000;
constexpr int NE = 3200000;
constexpr int NFINE = 1563;      // ceil(NN/64)
constexpr int NCOARSE = 49;      // ceil(NN/2048)
constexpr int NSLICE = 16;       // part2 slices per coarse segment
constexpr unsigned CAPC = 68608; // coarse region cap (mean 65536, +12 sigma)
constexpr unsigned CAPF = 2304;  // fine region cap (mean 2048, +5.7 sigma)
constexpr unsigned SLCAP = 4352; // part2 slice cap (ceil(CAPC/16)=4288)
constexpr int CAP = 3072;        // layer LDS edge capacity (> CAPF)
constexpr int SST = 136;         // S node stride (ushorts); 272B rows, 16B-aligned

typedef short bf16x8 __attribute__((ext_vector_type(8)));
typedef float f32x4 __attribute__((ext_vector_type(4)));

__device__ __forceinline__ short f2bf(float f) {
  union { float f; unsigned u; } v; v.f = f;
  unsigned r = v.u + 0x7FFFu + ((v.u >> 16) & 1u);  // RNE
  return (short)(r >> 16);
}

// K0: region cursor init.
__global__ void __launch_bounds__(256) init_kernel(
    unsigned* __restrict__ ccur, unsigned* __restrict__ fcur) {
  int i = blockIdx.x * 256 + threadIdx.x;
  if (i < NFINE) fcur[i] = (unsigned)i * CAPF;
  if (i < NCOARSE) ccur[i] = (unsigned)i * CAPC;
}

// K1: embed f32 -> bf16 table (once).
__global__ void __launch_bounds__(256) conv_kernel(
    const float* __restrict__ X, unsigned short* __restrict__ Xb) {
  int i = blockIdx.x * 256 + threadIdx.x;
  if (i < NN * 4) {
    float4 v = reinterpret_cast<const float4*>(X)[i];
    ushort4 o;
    o.x = (unsigned short)f2bf(v.x); o.y = (unsigned short)f2bf(v.y);
    o.z = (unsigned short)f2bf(v.z); o.w = (unsigned short)f2bf(v.w);
    reinterpret_cast<ushort4*>(Xb)[i] = o;
  }
}

// K2: coarse partition (dst>>11), LDS counting sort + coalesced run write.
// Entry = src | rel<<17 | (dst&2047)<<20.
__global__ void __launch_bounds__(256) part1_kernel(
    const int* __restrict__ src, const int* __restrict__ dst,
    const int* __restrict__ typ, unsigned* __restrict__ ccur,
    unsigned* __restrict__ buf1) {
  __shared__ unsigned hist[NCOARSE];
  __shared__ unsigned lst[NCOARSE];
  __shared__ unsigned gb[NCOARSE];
  __shared__ unsigned Es[4096];
  if (threadIdx.x < NCOARSE) hist[threadIdx.x] = 0u;
  __syncthreads();
  const int base = blockIdx.x * 4096;
  unsigned ent[16], cb[16], rk[16];
#pragma unroll
  for (int i = 0; i < 16; ++i) {
    int e = base + i * 256 + threadIdx.x;
    if (e < NE) {
      unsigned d = (unsigned)dst[e];
      ent[i] = (unsigned)src[e] | ((unsigned)typ[e] << 17) | ((d & 2047u) << 20);
      cb[i] = d >> 11;
      rk[i] = atomicAdd(&hist[cb[i]], 1u);
    } else cb[i] = 0xFFFFFFFFu;
  }
  __syncthreads();
  // Wave 0: exclusive scan of 49 bins + global region-cursor grab.
  if (threadIdx.x < 64) {
    unsigned v = (threadIdx.x < NCOARSE) ? hist[threadIdx.x] : 0u;
    unsigned incl = v;
#pragma unroll
    for (int d2 = 1; d2 < 64; d2 <<= 1) {
      unsigned t = __shfl_up(incl, d2, 64);
      if (threadIdx.x >= d2) incl += t;
    }
    if (threadIdx.x < NCOARSE) {
      lst[threadIdx.x] = incl - v;
      gb[threadIdx.x] = v ? atomicAdd(&ccur[threadIdx.x], v) : 0u;
    }
  }
  __syncthreads();
  // Scatter into sorted LDS buffer (bank-parallel).
#pragma unroll
  for (int i = 0; i < 16; ++i)
    if (cb[i] != 0xFFFFFFFFu) Es[lst[cb[i]] + rk[i]] = ent[i];
  __syncthreads();
  // Coalesced run write-out: consecutive threads -> consecutive slots.
  for (int c = 0; c < NCOARSE; ++c) {
    unsigned n = hist[c], g0 = gb[c], l0 = lst[c];
    unsigned lim = (unsigned)(c + 1) * CAPC;
    for (unsigned i = threadIdx.x; i < n; i += 256) {
      unsigned pos = g0 + i;
      if (pos < lim) buf1[pos] = Es[l0 + i];
    }
  }
}

// K3: fine partition per coarse slice: LDS counting sort (32 bins) +
// coalesced run write into fixed fine regions. Final entry = low 26 bits.
__global__ void __launch_bounds__(256) part2_kernel(
    const unsigned* __restrict__ buf1, const unsigned* __restrict__ ccur,
    unsigned* __restrict__ fcur, unsigned* __restrict__ buf2) {
  __shared__ unsigned h[32], lst[32], gb[32], cur[32];
  __shared__ unsigned Es[SLCAP];
  const int c = blockIdx.x >> 4, s = blockIdx.x & (NSLICE - 1);
  const unsigned b0 = (unsigned)c * CAPC;
  const unsigned len = ccur[c] - b0;
  const unsigned sl = (len + NSLICE - 1) / NSLICE;
  const unsigned lo = b0 + s * sl;
  unsigned hi = lo + sl;
  { unsigned b1 = b0 + len; if (hi > b1) hi = b1; }
  if (threadIdx.x < 32) { h[threadIdx.x] = 0u; cur[threadIdx.x] = 0u; }
  __syncthreads();
  for (unsigned p = lo + threadIdx.x; p < hi; p += 256)
    atomicAdd(&h[(buf1[p] >> 26) & 31u], 1u);
  __syncthreads();
  if (threadIdx.x < 64) {
    unsigned v = (threadIdx.x < 32) ? h[threadIdx.x] : 0u;
    unsigned incl = v;
#pragma unroll
    for (int d2 = 1; d2 < 32; d2 <<= 1) {
      unsigned t = __shfl_up(incl, d2, 64);
      if (threadIdx.x >= d2) incl += t;
    }
    if (threadIdx.x < 32) {
      lst[threadIdx.x] = incl - v;
      gb[threadIdx.x] = v ? atomicAdd(&fcur[c * 32 + threadIdx.x], v) : 0u;
    }
  }
  __syncthreads();
  // Re-read (L2-hot) and scatter into sorted LDS buffer.
  for (unsigned p = lo + threadIdx.x; p < hi; p += 256) {
    unsigned e = buf1[p];
    unsigned fl = (e >> 26) & 31u;
    unsigned pos = lst[fl] + atomicAdd(&cur[fl], 1u);
    if (pos < SLCAP) Es[pos] = e & 0x03FFFFFFu;
  }
  __syncthreads();
  // Coalesced run write-out into fine regions.
  for (int fl = 0; fl < 32; ++fl) {
    unsigned n = h[fl], g0 = gb[fl], l0 = lst[fl];
    unsigned lim = ((unsigned)c * 32u + (unsigned)fl + 1u) * CAPF;
    for (unsigned i = threadIdx.x; i < n; i += 256) {
      unsigned pos = g0 + i;
      if (pos < lim) buf2[pos] = Es[l0 + i];
    }
  }
}

// K4/K5: per-bucket layer (identical to round 11).
template <int MODE>
__global__ void __launch_bounds__(512) layer_kernel(
    const unsigned short* __restrict__ Xb, const float* __restrict__ W,
    const float* __restrict__ ROOT, const float* __restrict__ BIAS,
    const unsigned* __restrict__ fcur, const unsigned* __restrict__ buf2,
    unsigned short* __restrict__ Hout, float* __restrict__ Fout) {
  __shared__ unsigned short S[64 * SST];
  __shared__ unsigned E[CAP];
  __shared__ unsigned cnt512[512];
  __shared__ unsigned cur512[512];
  __shared__ unsigned wsum[8];
  const int tid = threadIdx.x;

  cnt512[tid] = 0u;
#pragma unroll
  for (int i = 0; i < CAP / 512; ++i) E[tid + i * 512] = 0u;
  __syncthreads();

  const unsigned p0 = (unsigned)blockIdx.x * CAPF;
  const int seg = (int)(fcur[blockIdx.x] - p0);

  unsigned e_0 = 0xFFFFFFFFu, e_1 = 0xFFFFFFFFu, e_2 = 0xFFFFFFFFu,
           e_3 = 0xFFFFFFFFu, e_4 = 0xFFFFFFFFu;
  if (tid < seg)          e_0 = buf2[p0 + tid];
  if (tid + 512 < seg)    e_1 = buf2[p0 + tid + 512];
  if (tid + 1024 < seg)   e_2 = buf2[p0 + tid + 1024];
  if (tid + 1536 < seg)   e_3 = buf2[p0 + tid + 1536];
  if (tid + 2048 < seg)   e_4 = buf2[p0 + tid + 2048];
  auto BIN = [](unsigned e) -> unsigned { return (e >> 17) & 511u; };
  auto HB = [&](unsigned e) {
    if (e != 0xFFFFFFFFu) atomicAdd(&cnt512[BIN(e)], 1u);
  };
  HB(e_0); HB(e_1); HB(e_2); HB(e_3); HB(e_4);
  __syncthreads();

  unsigned own = cnt512[tid];
  unsigned incl = own;
#pragma unroll
  for (int d = 1; d < 64; d <<= 1) {
    unsigned t = __shfl_up(incl, d, 64);
    if ((tid & 63) >= d) incl += t;
  }
  if ((tid & 63) == 63) wsum[tid >> 6] = incl;
  __syncthreads();
  unsigned pre = 0;
#pragma unroll
  for (int wv = 0; wv < 8; ++wv)
    pre += (wv < (tid >> 6)) ? wsum[wv] : 0u;
  cur512[tid] = pre + incl - own;
  __syncthreads();

  auto SC = [&](unsigned e) {
    if (e != 0xFFFFFFFFu) {
      unsigned pos = atomicAdd(&cur512[BIN(e)], 1u);
      if (pos < (unsigned)CAP) E[pos] = e;
    }
  };
  SC(e_0); SC(e_1); SC(e_2); SC(e_3); SC(e_4);
  __syncthreads();

  const int w = tid >> 6;
  const int lane = tid & 63;
  const int rc = lane & 15;
  const int quad = lane >> 4;

  for (int pq = 0; pq < 4; ++pq) {
    const int pp = w * 4 + pq;
    const int pb = pp * 16;
    const int beg = (int)(cur512[pb] - cnt512[pb]);
    const int end = (int)cur512[pb + 15];
    const unsigned rowbin = (unsigned)(pb + rc);

    f32x4 acc = {0.f, 0.f, 0.f, 0.f};
    int p = beg;
    for (; p + 32 <= end; p += 32) {
      bf16x8 af, bv;
#pragma unroll
      for (int j = 0; j < 8; ++j) {
        unsigned e = E[p + quad * 8 + j];
        af[j] = (((e >> 17) & 511u) == rowbin) ? (short)0x3F80 : (short)0;
        bv[j] = (short)Xb[(size_t)(e & 0x1FFFFu) * 16 + rc];
      }
      acc = __builtin_amdgcn_mfma_f32_16x16x32_bf16(af, bv, acc, 0, 0, 0);
    }
    if (p < end) {
      bf16x8 af, bv;
#pragma unroll
      for (int j = 0; j < 8; ++j) {
        int q = p + quad * 8 + j;
        unsigned e = E[q < CAP ? q : 0];
        bool v = q < end;
        af[j] = (v && ((e >> 17) & 511u) == rowbin) ? (short)0x3F80 : (short)0;
        bv[j] = (short)Xb[(size_t)(e & 0x1FFFFu) * 16 + rc];
      }
      acc = __builtin_amdgcn_mfma_f32_16x16x32_bf16(af, bv, acc, 0, 0, 0);
    }

#pragma unroll
    for (int r2 = 0; r2 < 4; ++r2) {
      int gbin = pb + quad * 4 + r2;
      unsigned ct = cnt512[gbin];
      float iv = 1.f / (float)(ct ? ct : 1u);
      int nd = gbin >> 3, rl = gbin & 7;
      S[nd * SST + rl * 16 + rc] = (unsigned short)f2bf(acc[r2] * iv);
    }
  }
  __syncthreads();

  if (w >= 4) return;
  const int fc = lane & 15;
  const int g = lane >> 4;
  const int n0 = blockIdx.x * 64 + w * 16;

  bf16x8 b0, b1, b2, b3, brt;
#pragma unroll
  for (int j = 0; j < 8; ++j) {
    int kq = g * 8 + j; int rb = kq >> 4; int kk = kq & 15;
    b0[j] = f2bf(W[(rb + 0) * 256 + kk * 16 + fc]);
    b1[j] = f2bf(W[(rb + 2) * 256 + kk * 16 + fc]);
    b2[j] = f2bf(W[(rb + 4) * 256 + kk * 16 + fc]);
    b3[j] = f2bf(W[(rb + 6) * 256 + kk * 16 + fc]);
    brt[j] = (kq < 16) ? f2bf(ROOT[kq * 16 + fc]) : (short)0;
  }

  const int kk0 = (g & 1) * 8;
  const int rsel = g >> 1;
  const int dl16 = w * 16 + fc;
  bf16x8 a0, a1, a2, a3;
#define LDA(AM, M)                                                        \
  {                                                                       \
    const unsigned short* sp2 = S + dl16 * SST + (2 * (M) + rsel) * 16 + kk0; \
    AM = *reinterpret_cast<const bf16x8*>(sp2);                           \
  }
  LDA(a0, 0) LDA(a1, 1) LDA(a2, 2) LDA(a3, 3)
#undef LDA

  bf16x8 ar = {0, 0, 0, 0, 0, 0, 0, 0};
  if (g < 2) {
    int node = n0 + fc;
    if (node < NN)
      ar = *reinterpret_cast<const bf16x8*>(Xb + (size_t)node * 16 + g * 8);
  }

  const float bc = BIAS[fc];
  f32x4 acc = {bc, bc, bc, bc};
  acc = __builtin_amdgcn_mfma_f32_16x16x32_bf16(a0, b0, acc, 0, 0, 0);
  acc = __builtin_amdgcn_mfma_f32_16x16x32_bf16(a1, b1, acc, 0, 0, 0);
  acc = __builtin_amdgcn_mfma_f32_16x16x32_bf16(a2, b2, acc, 0, 0, 0);
  acc = __builtin_amdgcn_mfma_f32_16x16x32_bf16(a3, b3, acc, 0, 0, 0);
  acc = __builtin_amdgcn_mfma_f32_16x16x32_bf16(ar, brt, acc, 0, 0, 0);

  if (MODE == 0) {
#pragma unroll
    for (int r2 = 0; r2 < 4; ++r2) {
      int node = n0 + g * 4 + r2;
      if (node < NN)
        Hout[(size_t)node * 16 + fc] = (unsigned short)f2bf(fmaxf(acc[r2], 0.f));
    }
  } else {
#pragma unroll
    for (int r2 = 0; r2 < 4; ++r2) {
      int node = n0 + g * 4 + r2;
      float zv = acc[r2];
      float mx = zv;
      mx = fmaxf(mx, __shfl_xor(mx, 1));
      mx = fmaxf(mx, __shfl_xor(mx, 2));
      mx = fmaxf(mx, __shfl_xor(mx, 4));
      mx = fmaxf(mx, __shfl_xor(mx, 8));
      float sm = expf(zv - mx);
      sm += __shfl_xor(sm, 1);
      sm += __shfl_xor(sm, 2);
      sm += __shfl_xor(sm, 4);
      sm += __shfl_xor(sm, 8);
      if (node < NN)
        Fout[(size_t)node * 16 + fc] = zv - mx - logf(sm);
    }
  }
}

extern "C" void kernel_launch(void* const* d_in, const int* in_sizes, int n_in,
                              void* d_out, int out_size, void* d_ws, size_t ws_size,
                              hipStream_t stream) {
  const float* embed = (const float*)d_in[0];
  const float* W1    = (const float*)d_in[1];
  const float* root1 = (const float*)d_in[2];
  const float* b1    = (const float*)d_in[3];
  const float* W2    = (const float*)d_in[4];
  const float* root2 = (const float*)d_in[5];
  const float* b2    = (const float*)d_in[6];
  const int* eidx    = (const int*)d_in[7];
  const int* etyp    = (const int*)d_in[8];
  const int* src = eidx;
  const int* dst = eidx + NE;
  float* out = (float*)d_out;

  // ws (u32): ccur[64] fcur[1600] buf1[49*CAPC] buf2[1563*CAPF]  (~27.9 MB)
  // buf1 (dead after part2) hosts h (bf16, first 800K u32) and xb (bf16
  // embed, next 800K u32); remaining space is scratch.
  unsigned* ccur = (unsigned*)d_ws;
  unsigned* fcur = ccur + 64;
  unsigned* buf1 = fcur + 1600;
  unsigned* buf2 = buf1 + (size_t)NCOARSE * CAPC;
  unsigned short* h  = (unsigned short*)buf1;
  unsigned short* xb = (unsigned short*)(buf1 + 800000);

  init_kernel<<<7, 256, 0, stream>>>(ccur, fcur);
  part1_kernel<<<782, 256, 0, stream>>>(src, dst, etyp, ccur, buf1);
  part2_kernel<<<NCOARSE * NSLICE, 256, 0, stream>>>(buf1, ccur, fcur, buf2);
  conv_kernel<<<1563, 256, 0, stream>>>(embed, xb);   // buf1 payload dead now
  layer_kernel<0><<<NFINE, 512, 0, stream>>>(xb, W1, root1, b1, fcur,
                                             buf2, h, out);
  layer_kernel<1><<<NFINE, 512, 0, stream>>>(h, W2, root2, b2, fcur,
                                             buf2, h, out);
}